// Round 1
// 221.327 us; speedup vs baseline: 1.4765x; 1.4765x over previous
//
#include <hip/hip_runtime.h>

typedef __attribute__((ext_vector_type(8))) short short8;
typedef __attribute__((ext_vector_type(4))) short short4v;
typedef __attribute__((ext_vector_type(4))) float floatx4;

#define NWSIDE 14
#define HLEN   56
#define DM     256

// Per-window LDS (bf16 elems): Q[16][264] @0, K[16][264] @4224, VT[256][16] @8448
// xs (staged x, bf16) overlays the Q region; O (fp32) overlays Q+K after attention reads.
#define QK_STRIDE 264
#define K_OFF     4224
#define VT_OFF    8448
#define WINELEMS  12544          // x2 windows = 25088 elems = 50176 B -> 3 blocks/CU
#define OW_F      6272           // fp32 stride per window for O staging (25088B/4)

static __device__ __forceinline__ unsigned int f2bfu(float f) {
    unsigned int u = __float_as_uint(f);
    return (u + 0x7fffu + ((u >> 16) & 1u)) >> 16;    // RNE
}
static __device__ __forceinline__ unsigned short f2bf(float f) {
    return (unsigned short)f2bfu(f);
}

// prep: fragment-ordered weights.
// WtF[((t*8 + ks)*64 + lane)*8 + j] = W[k][c],  where
//   col' = t*16 + (lane&15), k = ks*32 + (lane>>4)*8 + j,
//   c = h*96 + e*3 + sect  for  col' = h*96 + sect*32 + e.
// Grid: 256 blocks (one k each) x 256 threads (c coalesced), 3 c per thread.
__global__ void swin_prep(const float* __restrict__ W, const float* __restrict__ bias,
                          unsigned short* __restrict__ Wt, float* __restrict__ bperm) {
    const int k = blockIdx.x;                       // 0..255
    const int ks = k >> 5, lq = (k >> 3) & 3, j = k & 7;
    #pragma unroll
    for (int it = 0; it < 3; ++it) {
        const int c = it * 256 + threadIdx.x;       // 0..767, coalesced read
        const float w = W[(size_t)k * 768 + c];
        const int h = c / 96, r = c - h * 96;
        const int e = r / 3, sect = r - e * 3;
        const int cp = h * 96 + sect * 32 + e;      // col'
        const int t = cp >> 4, lrow = cp & 15;
        Wt[(size_t)(((t * 8 + ks) * 64 + lq * 16 + lrow) << 3) + j] = f2bf(w);
        if (k == 0) bperm[cp] = bias[c];
    }
}

// 3136 blocks (32 b x 98 pairs) x 256 threads (4 waves). 2 windows/block.
__global__ __launch_bounds__(256, 3)
void swin_mfma(const float* __restrict__ x,
               const unsigned short* __restrict__ Wt,
               const float* __restrict__ bperm,
               float* __restrict__ out) {
    __shared__ __align__(16) unsigned short lds[2 * WINELEMS];

    const int b    = blockIdx.x / 98;
    const int g    = blockIdx.x % 98;           // windows 2g, 2g+1
    const int tid  = threadIdx.x;
    const int wv   = tid >> 6;
    const int lane = tid & 63;
    const int lrow = lane & 15;
    const int lq   = lane >> 4;
    const float scale = 0.17677669529663687f;   // 1/sqrt(32)
    const floatx4 zf = {0.f, 0.f, 0.f, 0.f};

    // cooperative-phase mapping: thread -> (window u2, token tk, segment sg)
    const int u2 = tid >> 7, tk = (tid >> 3) & 15, sg = tid & 7;
    const int ww2 = g * 2 + u2;
    const int wi2 = ww2 / NWSIDE, wj2 = ww2 % NWSIDE;
    const int gr2 = (wi2 * 4 + (tk >> 2) + 2) % HLEN;
    const int gc2 = (wj2 * 4 + (tk & 3) + 2) % HLEN;
    const size_t rowoff = ((size_t)(b * 3136 + gr2 * 56 + gc2)) * DM;

    // ---- phase 1: cooperative x load (contiguous 1KB token rows) -> bf16 LDS ----
    {
        const floatx4* xr = (const floatx4*)(x + rowoff);
        unsigned short* xd = &lds[u2 * WINELEMS + tk * QK_STRIDE];
        #pragma unroll
        for (int j = 0; j < 8; ++j) {
            floatx4 f = xr[sg + 8 * j];          // 128B contiguous per 8 lanes
            short4v p;
            p[0] = (short)f2bf(f[0]); p[1] = (short)f2bf(f[1]);
            p[2] = (short)f2bf(f[2]); p[3] = (short)f2bf(f[3]);
            *(short4v*)&xd[(sg + 8 * j) * 4] = p;
        }
    }
    __syncthreads();

    // prologue prefetch of tile 0's A-fragments + bias (overlaps phase-2 LDS reads;
    // the phase-2 -> phase-3 barrier drain absorbs the L2 latency)
    const unsigned short* wfp = Wt + (size_t)(wv * 12) * 4096 + (size_t)lane * 8;
    short8 Ac[8], An[8];
    #pragma unroll
    for (int ks = 0; ks < 8; ++ks) Ac[ks] = *(const short8*)(wfp + ks * 512);
    floatx4 bc = *(const floatx4*)&bperm[wv * 12 * 16 + lq * 4];
    floatx4 bn;

    // ---- phase 2: build MFMA B-fragments from LDS (conflict-free b128) ----
    short8 xf[2][8];
    #pragma unroll
    for (int u = 0; u < 2; ++u)
        #pragma unroll
        for (int ks = 0; ks < 8; ++ks)
            xf[u][ks] = *(const short8*)&lds[u * WINELEMS + lrow * QK_STRIDE + ks * 32 + lq * 8];
    __syncthreads();   // xs dead; Q region reusable

    // ---- phase 3: GEMM qkv^T, software-pipelined over n-tiles ----
    // wave wv owns n-tiles [12wv, 12wv+12); fragment loads are contiguous 1KB/wave.
    #pragma unroll
    for (int n = 0; n < 12; ++n) {
        const int t    = wv * 12 + n;
        const int col0 = t * 16;

        // prefetch tile n+1 (8 x 1KB contiguous loads + bias), independent of MFMAs
        if (n < 11) {
            const unsigned short* wnp = wfp + (size_t)(n + 1) * 4096;
            #pragma unroll
            for (int ks = 0; ks < 8; ++ks) An[ks] = *(const short8*)(wnp + ks * 512);
            bn = *(const floatx4*)&bperm[(t + 1) * 16 + lq * 4];
        }

        floatx4 acc0 = bc, acc1 = bc;
        #pragma unroll
        for (int ks = 0; ks < 8; ++ks) {
            acc0 = __builtin_amdgcn_mfma_f32_16x16x32_bf16(Ac[ks], xf[0][ks], acc0, 0, 0, 0);
            acc1 = __builtin_amdgcn_mfma_f32_16x16x32_bf16(Ac[ks], xf[1][ks], acc1, 0, 0, 0);
        }

        const int h    = t / 6;
        const int r    = col0 - h * 96;
        const int sect = r >> 5;
        const int e0   = r & 31;
        // lane holds qkv[tok=lrow][col0 + lq*4 + i]
        if (sect < 2) {
            const int base = (sect ? K_OFF : 0) + lrow * QK_STRIDE + h * 32 + e0 + lq * 4;
            short4v p0, p1;
            p0[0] = (short)f2bf(acc0[0]); p0[1] = (short)f2bf(acc0[1]);
            p0[2] = (short)f2bf(acc0[2]); p0[3] = (short)f2bf(acc0[3]);
            p1[0] = (short)f2bf(acc1[0]); p1[1] = (short)f2bf(acc1[1]);
            p1[2] = (short)f2bf(acc1[2]); p1[3] = (short)f2bf(acc1[3]);
            *(short4v*)&lds[base]            = p0;
            *(short4v*)&lds[WINELEMS + base] = p1;
        } else {
            #pragma unroll
            for (int i = 0; i < 4; ++i) {
                const int rowe = h * 32 + e0 + lq * 4 + i;
                lds[VT_OFF + rowe * 16 + lrow]            = f2bf(acc0[i]);
                lds[WINELEMS + VT_OFF + rowe * 16 + lrow] = f2bf(acc1[i]);
            }
        }

        if (n < 11) {
            #pragma unroll
            for (int ks = 0; ks < 8; ++ks) Ac[ks] = An[ks];
            bc = bn;
        }
    }
    __syncthreads();

    // ---- phase 4: S^T precompute (all Q/K reads happen here) ----
    const int u     = wv >> 1;
    const int hbase = (wv & 1) * 4;
    const int ww = g * 2 + u;
    const int wi = ww / NWSIDE, wj = ww % NWSIDE;
    const bool lastrow = (wi == NWSIDE - 1);
    const bool lastcol = (wj == NWSIDE - 1);
    const unsigned short* wl = lds + u * WINELEMS;
    const bool mrow = lastrow && ((lrow >= 8) != (lq >= 2));
    const bool mc   = ((lrow & 3) >= 2);
    const int vtq = (lq & 1) * 8;

    floatx4 ST[4];
    #pragma unroll
    for (int hh = 0; hh < 4; ++hh) {
        const int h = hbase + hh;
        short8 Ak = *(const short8*)&wl[K_OFF + lrow * QK_STRIDE + h * 32 + lq * 8];
        short8 Bq = *(const short8*)&wl[lrow * QK_STRIDE + h * 32 + lq * 8];
        ST[hh] = __builtin_amdgcn_mfma_f32_16x16x32_bf16(Ak, Bq, zf, 0, 0, 0);
    }
    __syncthreads();   // Q/K dead; O staging may overwrite

    // ---- phase 5: softmax + PV, O -> LDS (fp32, over old Q+K region) ----
    float* Of = (float*)lds;
    #pragma unroll
    for (int hh = 0; hh < 4; ++hh) {
        const int h = hbase + hh;
        // lane holds S^T[s = lq*4+i][t = lrow]
        float ev[4];
        #pragma unroll
        for (int i = 0; i < 4; ++i) {
            bool m = mrow || (lastcol && (mc != (i >= 2)));
            ev[i] = __expf(m ? -1e30f : ST[hh][i] * scale);
        }
        float rs = (ev[0] + ev[1]) + (ev[2] + ev[3]);
        rs += __shfl_xor(rs, 16);
        rs += __shfl_xor(rs, 32);
        const float inv = 1.0f / rs;
        const unsigned int d0 = f2bfu(ev[0] * inv) | (f2bfu(ev[1] * inv) << 16);
        const unsigned int d1 = f2bfu(ev[2] * inv) | (f2bfu(ev[3] * inv) << 16);
        // P^T B-fragment: lane needs s = lq*8 + j (j 0..7); zero for lq>=2
        const int src0 = lrow + ((lq & 1) << 5);
        int b0 = __shfl((int)d0, src0);
        int b1 = __shfl((int)d1, src0);
        int b2 = __shfl((int)d0, src0 + 16);
        int b3 = __shfl((int)d1, src0 + 16);
        if (lq >= 2) { b0 = 0; b1 = 0; b2 = 0; b3 = 0; }
        union { int i4[4]; short8 s8; } bp;
        bp.i4[0] = b0; bp.i4[1] = b1; bp.i4[2] = b2; bp.i4[3] = b3;
        #pragma unroll
        for (int eb = 0; eb < 2; ++eb) {
            short8 Av = *(const short8*)&wl[VT_OFF + (h * 32 + eb * 16 + lrow) * 16 + vtq];
            floatx4 O = __builtin_amdgcn_mfma_f32_16x16x32_bf16(Av, bp.s8, zf, 0, 0, 0);
            // lane holds O[t=lrow][e = eb*16 + lq*4 + i]
            *(floatx4*)&Of[u * OW_F + lrow * QK_STRIDE + h * 32 + eb * 16 + lq * 4] = O;
        }
    }
    __syncthreads();

    // ---- phase 6: cooperative store (contiguous 1KB token rows) ----
    {
        float* op = out + rowoff;
        const float* Os = &Of[u2 * OW_F + tk * QK_STRIDE];
        #pragma unroll
        for (int j = 0; j < 8; ++j)
            *(floatx4*)&op[(sg + 8 * j) * 4] = *(const floatx4*)&Os[(sg + 8 * j) * 4];
    }
}

extern "C" void kernel_launch(void* const* d_in, const int* in_sizes, int n_in,
                              void* d_out, int out_size, void* d_ws, size_t ws_size,
                              hipStream_t stream) {
    const float* x    = (const float*)d_in[0];
    const float* W    = (const float*)d_in[1];
    const float* bias = (const float*)d_in[2];
    float* out = (float*)d_out;
    (void)in_sizes; (void)n_in; (void)out_size; (void)ws_size;

    unsigned short* Wt = (unsigned short*)d_ws;                // 393216 B (fragment order)
    float* bperm = (float*)((char*)d_ws + 768 * 256 * 2);      // +3072 B

    swin_prep<<<256, 256, 0, stream>>>(W, bias, Wt, bperm);
    swin_mfma<<<32 * 98, 256, 0, stream>>>(x, Wt, bperm, out);
}